// Round 4
// baseline (113.093 us; speedup 1.0000x reference)
//
#include <hip/hip_runtime.h>
#include <math.h>

// Additive attention, MI355X. B=4, Q=K=1024, QSIZE=KSIZE=256, H=32, VDIM=256.
//
// Math: tanh(fq+fk) = 1 - 2/(1 + e^{2fq} e^{2fk}); precompute eq=e^{2fq}, ek=e^{2fk}.
// score = const - 2*sum_h w_h/u_h, u_h = 1 + eq_h ek_h; const cancels in softmax.
// Rational 2-level combine -> 1 rcp per 4 h. Masked k skipped; normalization deferred.
//
// R4: (a) XCD swizzle in attn: blockIdx%8 round-robins XCDs, so force batch
//     b = (blockIdx&7)&3 -> each XCD reads ONE batch's 4 MB values slab = L2-resident
//     (was 16 MB working set in 4 MB L2 -> thrash).
//     (b) proj: 4 rows/thread x 32-dim slice -> W traffic /4 (268->67 MB).

#define NB 4
#define NQ 1024
#define NK 1024
#define DQK 256
#define NH 32
#define NV 256
#define TQ 8    // q-rows per attn block
#define BLK 512 // attn block size (8 waves)

__device__ __forceinline__ float fast_rcp(float x) { return __builtin_amdgcn_rcpf(x); }

// ---------------------------------------------------------------------------
// Kernel 1: projections + exp(2x).
// Thread = (4-row group, h-group of 4, eighth of dims = 32 dims).
// 2048 rowgroups * 8 hgroups * 8 eighths = 131072 threads = 512 blocks.
__global__ __launch_bounds__(256) void proj_kernel(
    const float* __restrict__ queries, const float* __restrict__ keys,
    const float* __restrict__ W_q, const float* __restrict__ b_q,
    const float* __restrict__ W_k, const float* __restrict__ b_k,
    float* __restrict__ eq, float* __restrict__ ek)
{
    const int tid    = blockIdx.x * 256 + threadIdx.x;
    const int sub    = tid & 63;           // lane
    const int h4     = (sub & 7) * 4;      // h-group base
    const int eighth = sub >> 3;           // 0..7 -> dims eighth*32..+31
    const int rg     = tid >> 6;           // 0..2047 rowgroup (4 rows)

    const float* srcb; const float* W; const float* bias; float* dst; int r0;
    if (rg < 1024) { r0 = rg * 4;        srcb = queries; W = W_q; bias = b_q; dst = eq; }
    else           { r0 = (rg - 1024)*4; srcb = keys;    W = W_k; bias = b_k; dst = ek; }
    const float* src0 = srcb + (size_t)r0 * DQK;
    const float* src1 = src0 + DQK;
    const float* src2 = src1 + DQK;
    const float* src3 = src2 + DQK;

    float a00=0,a01=0,a02=0,a03=0, a10=0,a11=0,a12=0,a13=0;
    float a20=0,a21=0,a22=0,a23=0, a30=0,a31=0,a32=0,a33=0;

    const int d0 = eighth * 32;
    #pragma unroll
    for (int i = d0; i < d0 + 32; i += 4) {
        float4 w0 = *(const float4*)(W + (size_t)(i + 0) * NH + h4);
        float4 w1 = *(const float4*)(W + (size_t)(i + 1) * NH + h4);
        float4 w2 = *(const float4*)(W + (size_t)(i + 2) * NH + h4);
        float4 w3 = *(const float4*)(W + (size_t)(i + 3) * NH + h4);
        float4 s0 = *(const float4*)(src0 + i);
        float4 s1 = *(const float4*)(src1 + i);
        float4 s2 = *(const float4*)(src2 + i);
        float4 s3 = *(const float4*)(src3 + i);
#define ROW(A0,A1,A2,A3,S) \
        A0 = fmaf(S.x, w0.x, A0); A1 = fmaf(S.x, w0.y, A1); A2 = fmaf(S.x, w0.z, A2); A3 = fmaf(S.x, w0.w, A3); \
        A0 = fmaf(S.y, w1.x, A0); A1 = fmaf(S.y, w1.y, A1); A2 = fmaf(S.y, w1.z, A2); A3 = fmaf(S.y, w1.w, A3); \
        A0 = fmaf(S.z, w2.x, A0); A1 = fmaf(S.z, w2.y, A1); A2 = fmaf(S.z, w2.z, A2); A3 = fmaf(S.z, w2.w, A3); \
        A0 = fmaf(S.w, w3.x, A0); A1 = fmaf(S.w, w3.y, A1); A2 = fmaf(S.w, w3.z, A2); A3 = fmaf(S.w, w3.w, A3);
        ROW(a00,a01,a02,a03,s0) ROW(a10,a11,a12,a13,s1)
        ROW(a20,a21,a22,a23,s2) ROW(a30,a31,a32,a33,s3)
#undef ROW
    }
    // reduce over eighth (lane bits 3,4,5)
#define RED(A) A += __shfl_xor(A, 8, 64); A += __shfl_xor(A, 16, 64); A += __shfl_xor(A, 32, 64);
    RED(a00) RED(a01) RED(a02) RED(a03) RED(a10) RED(a11) RED(a12) RED(a13)
    RED(a20) RED(a21) RED(a22) RED(a23) RED(a30) RED(a31) RED(a32) RED(a33)
#undef RED
    if (eighth == 0) {
        float4 bv = *(const float4*)(bias + h4);
        float4 o;
        float* d = dst + (size_t)r0 * NH + h4;
        o.x = __expf(2.f*(a00+bv.x)); o.y = __expf(2.f*(a01+bv.y));
        o.z = __expf(2.f*(a02+bv.z)); o.w = __expf(2.f*(a03+bv.w));
        *(float4*)(d) = o;
        o.x = __expf(2.f*(a10+bv.x)); o.y = __expf(2.f*(a11+bv.y));
        o.z = __expf(2.f*(a12+bv.z)); o.w = __expf(2.f*(a13+bv.w));
        *(float4*)(d + NH) = o;
        o.x = __expf(2.f*(a20+bv.x)); o.y = __expf(2.f*(a21+bv.y));
        o.z = __expf(2.f*(a22+bv.z)); o.w = __expf(2.f*(a23+bv.w));
        *(float4*)(d + 2*NH) = o;
        o.x = __expf(2.f*(a30+bv.x)); o.y = __expf(2.f*(a31+bv.y));
        o.z = __expf(2.f*(a32+bv.z)); o.w = __expf(2.f*(a33+bv.w));
        *(float4*)(d + 3*NH) = o;
    }
}

// ---------------------------------------------------------------------------
// Kernel 2: fused scores + softmax + weighted sum over values.
// Block = 512 threads (8 waves), handles (b, TQ=8 q-rows). grid = 512.
// XCD swizzle: x = blockIdx&7 selects XCD (dispatch round-robin); b = x&3 so
// each XCD touches exactly one batch's values slab (4 MB = one XCD L2).
// Wave w owns k-range [w*kpw, ...) for BOTH score and BMM phases -> no
// inter-wave sync until the final reduction.
__global__ __launch_bounds__(BLK, 4) void attn_kernel(
    const float* __restrict__ eq, const float* __restrict__ ek,
    const float* __restrict__ values, const int* __restrict__ valid_lens,
    const float* __restrict__ w_v, float* __restrict__ out)
{
    __shared__ float s_w[NK][TQ];     // 32 KB: unnormalized exp-weights [k][q]; reused for partials
    __shared__ float s_part[8][TQ];   // per-wave softmax denominator partials

    const int t  = threadIdx.x;
    const int x  = blockIdx.x & 7;
    const int j  = blockIdx.x >> 3;             // 0..63
    const int b  = x & 3;
    const int q0 = (j + ((x >> 2) << 6)) * TQ;  // q-block 0..127
    const int nvalid = valid_lens[b];           // [1, 1024]
    const int wave   = t >> 6;
    const int lane   = t & 63;
    const int qi     = lane & 7;
    const int kk     = lane >> 3;               // 0..7

    const int kpw  = (nvalid + 7) >> 3;
    const int kbeg = wave * kpw;
    const int kend = min(nvalid, kbeg + kpw);

    float wv[NH];
    #pragma unroll
    for (int h = 0; h < NH; h += 4) {
        float4 w4 = *(const float4*)(w_v + h);
        wv[h] = w4.x; wv[h+1] = w4.y; wv[h+2] = w4.z; wv[h+3] = w4.w;
    }
    float eqr[NH];
    const float* eqp = eq + (size_t)(b * NQ + q0 + qi) * NH;
    #pragma unroll
    for (int h = 0; h < NH; h += 4) {
        float4 e4 = *(const float4*)(eqp + h);
        eqr[h] = e4.x; eqr[h+1] = e4.y; eqr[h+2] = e4.z; eqr[h+3] = e4.w;
    }

    // ---- scores + exp -> unnormalized weights into this wave's s_w region
    const float* ekbase = ek + (size_t)b * NK * NH;
    float ssum = 0.f;
    for (int k0 = kbeg; k0 < kend; k0 += 8) {
        const int k = k0 + kk;
        if (k < kend) {
            const float* ekp = ekbase + (size_t)k * NH;
            float acc = 0.f;
            #pragma unroll
            for (int h = 0; h < NH; h += 4) {
                float4 e4 = *(const float4*)(ekp + h);
                float u0 = fmaf(eqr[h+0], e4.x, 1.f);
                float u1 = fmaf(eqr[h+1], e4.y, 1.f);
                float u2 = fmaf(eqr[h+2], e4.z, 1.f);
                float u3 = fmaf(eqr[h+3], e4.w, 1.f);
                float d01 = u0 * u1, d23 = u2 * u3;
                float n01 = fmaf(wv[h+0], u1, wv[h+1] * u0);
                float n23 = fmaf(wv[h+2], u3, wv[h+3] * u2);
                float d   = fminf(d01 * d23, 1e38f);   // inf guard
                float n   = fmaf(n01, d23, n23 * d01);
                acc = fmaf(n, fast_rcp(d), acc);
            }
            float e = __expf(-2.f * acc);
            s_w[k][qi] = e;          // lane mod 32 -> 2-way alias = free
            ssum += e;
        }
    }

    // per-wave softmax denominator partial (reduce over kk = lane bits 3..5)
    ssum += __shfl_xor(ssum, 8, 64);
    ssum += __shfl_xor(ssum, 16, 64);
    ssum += __shfl_xor(ssum, 32, 64);
    if (lane < TQ) s_part[wave][lane] = ssum;

    // ---- bmm over the same k-range (weights written by THIS wave: no barrier)
    float4 acc0 = {0,0,0,0}, acc1 = {0,0,0,0}, acc2 = {0,0,0,0}, acc3 = {0,0,0,0};
    float4 acc4 = {0,0,0,0}, acc5 = {0,0,0,0}, acc6 = {0,0,0,0}, acc7 = {0,0,0,0};
    const float* vbase = values + (size_t)b * NK * NV + 4 * lane;

#define FMA4(A, W) A.x = fmaf((W), v.x, A.x); A.y = fmaf((W), v.y, A.y); \
                   A.z = fmaf((W), v.z, A.z); A.w = fmaf((W), v.w, A.w);
    #pragma unroll 4
    for (int k = kbeg; k < kend; k++) {
        float4 v  = *(const float4*)(vbase + (size_t)k * NV);
        float4 w0 = *(const float4*)(&s_w[k][0]);   // wave-uniform broadcast
        float4 w1 = *(const float4*)(&s_w[k][4]);
        FMA4(acc0, w0.x); FMA4(acc1, w0.y); FMA4(acc2, w0.z); FMA4(acc3, w0.w);
        FMA4(acc4, w1.x); FMA4(acc5, w1.y); FMA4(acc6, w1.z); FMA4(acc7, w1.w);
    }
#undef FMA4

    __syncthreads();                 // everyone done with s_w as weights
    float* sred = &s_w[0][0];        // reuse 32 KB as [4 regions][q][256] partials
    float4* p = (float4*)(sred + (size_t)((wave & 3) * TQ) * 256) + lane;
    if (wave < 4) {                  // round A: waves 0..3 write their partials
        p[0*64] = acc0; p[1*64] = acc1; p[2*64] = acc2; p[3*64] = acc3;
        p[4*64] = acc4; p[5*64] = acc5; p[6*64] = acc6; p[7*64] = acc7;
    }
    __syncthreads();
    if (wave >= 4) {                 // round B: waves 4..7 accumulate in place
        float4 x4;
#define ACC4(I, A) x4 = p[I*64]; x4.x += A.x; x4.y += A.y; x4.z += A.z; x4.w += A.w; p[I*64] = x4;
        ACC4(0, acc0); ACC4(1, acc1); ACC4(2, acc2); ACC4(3, acc3);
        ACC4(4, acc4); ACC4(5, acc5); ACC4(6, acc6); ACC4(7, acc7);
#undef ACC4
    }
    __syncthreads();

    // ---- final reduction over 4 regions + deferred normalization.
    const int v  = t & 255;
    const int qh = (t >> 8) * 4;
    float* obase = out + (size_t)(b * NQ + q0) * NV + v;
    #pragma unroll
    for (int jj = 0; jj < 4; jj++) {
        const int q = qh + jj;
        float tot = 0.f;
        #pragma unroll
        for (int w = 0; w < 8; w++) tot += s_part[w][q];
        float rs = fast_rcp(tot);
        float r = sred[(0*TQ + q) * 256 + v] + sred[(1*TQ + q) * 256 + v]
                + sred[(2*TQ + q) * 256 + v] + sred[(3*TQ + q) * 256 + v];
        obase[(size_t)q * NV] = r * rs;
    }
}

// ---------------------------------------------------------------------------
extern "C" void kernel_launch(void* const* d_in, const int* in_sizes, int n_in,
                              void* d_out, int out_size, void* d_ws, size_t ws_size,
                              hipStream_t stream) {
    (void)in_sizes; (void)n_in; (void)out_size; (void)ws_size;
    const float* keys       = (const float*)d_in[0];
    const float* queries    = (const float*)d_in[1];
    const float* values     = (const float*)d_in[2];
    const int*   valid_lens = (const int*)d_in[3];
    const float* W_q        = (const float*)d_in[4];
    const float* b_q        = (const float*)d_in[5];
    const float* W_k        = (const float*)d_in[6];
    const float* b_k        = (const float*)d_in[7];
    const float* w_v        = (const float*)d_in[8];
    // d_in[9] = b_v: cancels in softmax.
    float* out = (float*)d_out;

    float* eq = (float*)d_ws;                       // B*Q*32 floats
    float* ek = eq + (size_t)NB * NQ * NH;          // B*K*32 floats

    proj_kernel<<<dim3(512), dim3(256), 0, stream>>>(queries, keys, W_q, b_q, W_k, b_k, eq, ek);
    attn_kernel<<<dim3(NB * (NQ / TQ)), dim3(BLK), 0, stream>>>(eq, ek, values, valid_lens, w_v, out);
}

// Round 5
// 111.942 us; speedup vs baseline: 1.0103x; 1.0103x over previous
//
#include <hip/hip_runtime.h>
#include <math.h>

// Additive attention, MI355X. B=4, Q=K=1024, QSIZE=KSIZE=256, H=32, VDIM=256.
//
// Math: tanh(fq+fk) = 1 - 2/(1 + e^{2fq} e^{2fk}); precompute eq=e^{2fq}, ek=e^{2fk}.
// score = const - 2*sum_h w_h/u_h, u_h = 1 + eq_h ek_h; const cancels in softmax.
// Rational 2-level combine -> 1 rcp per 4 h. Masked k skipped; normalization deferred.
//
// R5: revert R4 (XCD-batch pinning caused valid_lens load imbalance; proj 4-row
// version halved blocks/CU). NEW: values converted once to bf16 (2 MB in ws) ->
// BMM's 262 MB of L3-served values re-reads halve to 131 MB. fp32 weights+accum
// keep the added error ~2e-3 (threshold 9.8e-3).

#define NB 4
#define NQ 1024
#define NK 1024
#define DQK 256
#define NH 32
#define NV 256
#define TQ 8    // q-rows per attn block
#define BLK 512 // attn block size (8 waves)

__device__ __forceinline__ float fast_rcp(float x) { return __builtin_amdgcn_rcpf(x); }

__device__ __forceinline__ unsigned short f32_to_bf16_rne(float f) {
    unsigned int u = __float_as_uint(f);
    return (unsigned short)((u + 0x7fffu + ((u >> 16) & 1u)) >> 16);
}

// ---------------------------------------------------------------------------
// Kernel 0: values fp32 -> bf16 (RNE). 4M elems, 8 per thread, 512 blocks.
__global__ __launch_bounds__(256) void cvt_kernel(
    const float* __restrict__ values, unsigned short* __restrict__ vbf)
{
    const size_t i = ((size_t)blockIdx.x * 256 + threadIdx.x) * 8;
    float4 a = *(const float4*)(values + i);
    float4 b = *(const float4*)(values + i + 4);
    union { unsigned short u[8]; uint4 v; } o;
    o.u[0] = f32_to_bf16_rne(a.x); o.u[1] = f32_to_bf16_rne(a.y);
    o.u[2] = f32_to_bf16_rne(a.z); o.u[3] = f32_to_bf16_rne(a.w);
    o.u[4] = f32_to_bf16_rne(b.x); o.u[5] = f32_to_bf16_rne(b.y);
    o.u[6] = f32_to_bf16_rne(b.z); o.u[7] = f32_to_bf16_rne(b.w);
    *(uint4*)(vbf + i) = o.v;
}

// ---------------------------------------------------------------------------
// Kernel 1: projections + exp(2x). Thread = (row, 4-h group, quarter of dims).
// 8192 rows * 8 hgroups * 4 quarters = 262144 threads = 1024 blocks. (R3 version)
__global__ __launch_bounds__(256) void proj_kernel(
    const float* __restrict__ queries, const float* __restrict__ keys,
    const float* __restrict__ W_q, const float* __restrict__ b_q,
    const float* __restrict__ W_k, const float* __restrict__ b_k,
    float* __restrict__ eq, float* __restrict__ ek)
{
    const int tid     = blockIdx.x * 256 + threadIdx.x;
    const int row     = tid >> 5;            // 0..8191
    const int sub     = tid & 31;
    const int h4      = (sub & 7) * 4;       // h-group
    const int quarter = sub >> 3;            // 0..3 -> dims quarter*64..+63

    const float* src; const float* W; const float* bias; float* dst; int r;
    if (row < NB * NQ) { r = row;           src = queries + (size_t)r * DQK; W = W_q; bias = b_q; dst = eq; }
    else               { r = row - NB * NQ; src = keys    + (size_t)r * DQK; W = W_k; bias = b_k; dst = ek; }

    float a0 = 0.f, a1 = 0.f, a2 = 0.f, a3 = 0.f;
    if (quarter == 0) {
        float4 bv4 = *(const float4*)(bias + h4);
        a0 = bv4.x; a1 = bv4.y; a2 = bv4.z; a3 = bv4.w;
    }
    const int d0 = quarter * 64;
    #pragma unroll 4
    for (int i = d0; i < d0 + 64; i += 4) {
        float4 s  = *(const float4*)(src + i);
        float4 w0 = *(const float4*)(W + (size_t)(i + 0) * NH + h4);
        float4 w1 = *(const float4*)(W + (size_t)(i + 1) * NH + h4);
        float4 w2 = *(const float4*)(W + (size_t)(i + 2) * NH + h4);
        float4 w3 = *(const float4*)(W + (size_t)(i + 3) * NH + h4);
        a0 = fmaf(s.x, w0.x, a0); a1 = fmaf(s.x, w0.y, a1); a2 = fmaf(s.x, w0.z, a2); a3 = fmaf(s.x, w0.w, a3);
        a0 = fmaf(s.y, w1.x, a0); a1 = fmaf(s.y, w1.y, a1); a2 = fmaf(s.y, w1.z, a2); a3 = fmaf(s.y, w1.w, a3);
        a0 = fmaf(s.z, w2.x, a0); a1 = fmaf(s.z, w2.y, a1); a2 = fmaf(s.z, w2.z, a2); a3 = fmaf(s.z, w2.w, a3);
        a0 = fmaf(s.w, w3.x, a0); a1 = fmaf(s.w, w3.y, a1); a2 = fmaf(s.w, w3.z, a2); a3 = fmaf(s.w, w3.w, a3);
    }
    a0 += __shfl_xor(a0, 8, 64);  a1 += __shfl_xor(a1, 8, 64);
    a2 += __shfl_xor(a2, 8, 64);  a3 += __shfl_xor(a3, 8, 64);
    a0 += __shfl_xor(a0, 16, 64); a1 += __shfl_xor(a1, 16, 64);
    a2 += __shfl_xor(a2, 16, 64); a3 += __shfl_xor(a3, 16, 64);
    if (quarter == 0) {
        float4 o;
        o.x = __expf(2.f * a0); o.y = __expf(2.f * a1);
        o.z = __expf(2.f * a2); o.w = __expf(2.f * a3);
        *(float4*)(dst + (size_t)r * NH + h4) = o;
    }
}

// ---------------------------------------------------------------------------
// Kernel 2: fused scores + softmax + weighted sum over values (bf16 values).
// Block = 512 threads (8 waves), handles (b, TQ=8 q-rows). grid = 4*128 = 512.
// Wave w owns k-range [w*kpw, ...) for BOTH score and BMM phases -> no
// inter-wave sync until the final reduction.
__global__ __launch_bounds__(BLK, 4) void attn_kernel(
    const float* __restrict__ eq, const float* __restrict__ ek,
    const unsigned short* __restrict__ vbf, const int* __restrict__ valid_lens,
    const float* __restrict__ w_v, float* __restrict__ out)
{
    __shared__ float s_w[NK][TQ];     // 32 KB: unnormalized exp-weights [k][q]; reused for partials
    __shared__ float s_part[8][TQ];   // per-wave softmax denominator partials

    const int t      = threadIdx.x;
    const int b      = blockIdx.x >> 7;
    const int q0     = (blockIdx.x & 127) * TQ;
    const int nvalid = valid_lens[b];           // [1, 1024]
    const int wave   = t >> 6;
    const int lane   = t & 63;
    const int qi     = lane & 7;
    const int kk     = lane >> 3;               // 0..7

    const int kpw  = (nvalid + 7) >> 3;
    const int kbeg = wave * kpw;
    const int kend = min(nvalid, kbeg + kpw);

    float wv[NH];
    #pragma unroll
    for (int h = 0; h < NH; h += 4) {
        float4 w4 = *(const float4*)(w_v + h);
        wv[h] = w4.x; wv[h+1] = w4.y; wv[h+2] = w4.z; wv[h+3] = w4.w;
    }
    float eqr[NH];
    const float* eqp = eq + (size_t)(b * NQ + q0 + qi) * NH;
    #pragma unroll
    for (int h = 0; h < NH; h += 4) {
        float4 e4 = *(const float4*)(eqp + h);
        eqr[h] = e4.x; eqr[h+1] = e4.y; eqr[h+2] = e4.z; eqr[h+3] = e4.w;
    }

    // ---- scores + exp -> unnormalized weights into this wave's s_w region
    const float* ekbase = ek + (size_t)b * NK * NH;
    float ssum = 0.f;
    for (int k0 = kbeg; k0 < kend; k0 += 8) {
        const int k = k0 + kk;
        if (k < kend) {
            const float* ekp = ekbase + (size_t)k * NH;
            float acc = 0.f;
            #pragma unroll
            for (int h = 0; h < NH; h += 4) {
                float4 e4 = *(const float4*)(ekp + h);
                float u0 = fmaf(eqr[h+0], e4.x, 1.f);
                float u1 = fmaf(eqr[h+1], e4.y, 1.f);
                float u2 = fmaf(eqr[h+2], e4.z, 1.f);
                float u3 = fmaf(eqr[h+3], e4.w, 1.f);
                float d01 = u0 * u1, d23 = u2 * u3;
                float n01 = fmaf(wv[h+0], u1, wv[h+1] * u0);
                float n23 = fmaf(wv[h+2], u3, wv[h+3] * u2);
                float d   = fminf(d01 * d23, 1e38f);   // inf guard
                float n   = fmaf(n01, d23, n23 * d01);
                acc = fmaf(n, fast_rcp(d), acc);
            }
            float e = __expf(-2.f * acc);
            s_w[k][qi] = e;          // lane mod 32 -> 2-way alias = free
            ssum += e;
        }
    }

    // per-wave softmax denominator partial (reduce over kk = lane bits 3..5)
    ssum += __shfl_xor(ssum, 8, 64);
    ssum += __shfl_xor(ssum, 16, 64);
    ssum += __shfl_xor(ssum, 32, 64);
    if (lane < TQ) s_part[wave][lane] = ssum;

    // ---- bmm over the same k-range (weights written by THIS wave: no barrier)
    // values in bf16: uint2 load (8 B) -> 4 fp32 via shift/mask.
    float4 acc0 = {0,0,0,0}, acc1 = {0,0,0,0}, acc2 = {0,0,0,0}, acc3 = {0,0,0,0};
    float4 acc4 = {0,0,0,0}, acc5 = {0,0,0,0}, acc6 = {0,0,0,0}, acc7 = {0,0,0,0};
    const unsigned short* vbase = vbf + (size_t)b * NK * NV + 4 * lane;

#define FMA4(A, W) A.x = fmaf((W), v.x, A.x); A.y = fmaf((W), v.y, A.y); \
                   A.z = fmaf((W), v.z, A.z); A.w = fmaf((W), v.w, A.w);
    #pragma unroll 4
    for (int k = kbeg; k < kend; k++) {
        uint2 raw = *(const uint2*)(vbase + (size_t)k * NV);
        float4 v;
        v.x = __uint_as_float(raw.x << 16);
        v.y = __uint_as_float(raw.x & 0xffff0000u);
        v.z = __uint_as_float(raw.y << 16);
        v.w = __uint_as_float(raw.y & 0xffff0000u);
        float4 w0 = *(const float4*)(&s_w[k][0]);   // wave-uniform broadcast
        float4 w1 = *(const float4*)(&s_w[k][4]);
        FMA4(acc0, w0.x); FMA4(acc1, w0.y); FMA4(acc2, w0.z); FMA4(acc3, w0.w);
        FMA4(acc4, w1.x); FMA4(acc5, w1.y); FMA4(acc6, w1.z); FMA4(acc7, w1.w);
    }
#undef FMA4

    __syncthreads();                 // everyone done with s_w as weights
    float* sred = &s_w[0][0];        // reuse 32 KB as [4 regions][q][256] partials
    float4* p = (float4*)(sred + (size_t)((wave & 3) * TQ) * 256) + lane;
    if (wave < 4) {                  // round A: waves 0..3 write their partials
        p[0*64] = acc0; p[1*64] = acc1; p[2*64] = acc2; p[3*64] = acc3;
        p[4*64] = acc4; p[5*64] = acc5; p[6*64] = acc6; p[7*64] = acc7;
    }
    __syncthreads();
    if (wave >= 4) {                 // round B: waves 4..7 accumulate in place
        float4 x4;
#define ACC4(I, A) x4 = p[I*64]; x4.x += A.x; x4.y += A.y; x4.z += A.z; x4.w += A.w; p[I*64] = x4;
        ACC4(0, acc0); ACC4(1, acc1); ACC4(2, acc2); ACC4(3, acc3);
        ACC4(4, acc4); ACC4(5, acc5); ACC4(6, acc6); ACC4(7, acc7);
#undef ACC4
    }
    __syncthreads();

    // ---- final reduction over 4 regions + deferred normalization.
    const int v  = t & 255;
    const int qh = (t >> 8) * 4;
    float* obase = out + (size_t)(b * NQ + q0) * NV + v;
    #pragma unroll
    for (int jj = 0; jj < 4; jj++) {
        const int q = qh + jj;
        float tot = 0.f;
        #pragma unroll
        for (int w = 0; w < 8; w++) tot += s_part[w][q];
        float rs = fast_rcp(tot);
        float r = sred[(0*TQ + q) * 256 + v] + sred[(1*TQ + q) * 256 + v]
                + sred[(2*TQ + q) * 256 + v] + sred[(3*TQ + q) * 256 + v];
        obase[(size_t)q * NV] = r * rs;
    }
}

// ---------------------------------------------------------------------------
extern "C" void kernel_launch(void* const* d_in, const int* in_sizes, int n_in,
                              void* d_out, int out_size, void* d_ws, size_t ws_size,
                              hipStream_t stream) {
    (void)in_sizes; (void)n_in; (void)out_size; (void)ws_size;
    const float* keys       = (const float*)d_in[0];
    const float* queries    = (const float*)d_in[1];
    const float* values     = (const float*)d_in[2];
    const int*   valid_lens = (const int*)d_in[3];
    const float* W_q        = (const float*)d_in[4];
    const float* b_q        = (const float*)d_in[5];
    const float* W_k        = (const float*)d_in[6];
    const float* b_k        = (const float*)d_in[7];
    const float* w_v        = (const float*)d_in[8];
    // d_in[9] = b_v: cancels in softmax.
    float* out = (float*)d_out;

    float* eq = (float*)d_ws;                                  // B*Q*32 floats (512 KB)
    float* ek = eq + (size_t)NB * NQ * NH;                     // B*K*32 floats (512 KB)
    unsigned short* vbf = (unsigned short*)(ek + (size_t)NB * NK * NH);  // B*K*256 bf16 (2 MB)

    cvt_kernel <<<dim3(512),  dim3(256), 0, stream>>>(values, vbf);
    proj_kernel<<<dim3(1024), dim3(256), 0, stream>>>(queries, keys, W_q, b_q, W_k, b_k, eq, ek);
    attn_kernel<<<dim3(NB * (NQ / TQ)), dim3(BLK), 0, stream>>>(eq, ek, vbf, valid_lens, w_v, out);
}

// Round 6
// 109.236 us; speedup vs baseline: 1.0353x; 1.0248x over previous
//
#include <hip/hip_runtime.h>
#include <math.h>

// Additive attention, MI355X. B=4, Q=K=1024, QSIZE=KSIZE=256, H=32, VDIM=256.
//
// Math: tanh(fq+fk) = 1 - 2/(1 + e^{2fq} e^{2fk}); precompute eq=e^{2fq}, ek=e^{2fk}.
// score = const - 2*sum_h w_h/u_h, u_h = 1 + eq_h ek_h; const cancels in softmax.
// Rational 2-level combine -> 1 rcp per 4 h. Masked k skipped; normalization deferred.
//
// R6: MFMA BMM. Weights -> bf16 [q][k] in LDS (k-contiguous = A-frag layout
// A[m=lane&15][k=quad*8+j]); values -> bf16 V^T [v][k] (B-frag 16B loads,
// B[k=quad*8+j][n=lane&15]); one mfma_f32_16x16x32_bf16 per 32 k's per v-tile.
// Each wave owns 32 v-cols over ALL k -> no cross-wave BMM reduction.
// V^T cvt fused into proj dispatch (block-uniform branch) to avoid a 3rd launch.

#define NB 4
#define NQ 1024
#define NK 1024
#define DQK 256
#define NH 32
#define NV 256
#define TQ 8     // q-rows per attn block
#define BLK 512  // attn block size (8 waves)
#define KSTR 1032 // s_w16 k-stride (bf16 elems): breaks power-of-2 banking

typedef __attribute__((ext_vector_type(8))) short bf16x8;
typedef __attribute__((ext_vector_type(4))) float f32x4;

__device__ __forceinline__ float fast_rcp(float x) { return __builtin_amdgcn_rcpf(x); }

__device__ __forceinline__ unsigned int f32_to_bf16_rne(float f) {
    unsigned int u = __float_as_uint(f);
    return (u + 0x7fffu + ((u >> 16) & 1u)) >> 16;
}

// ---------------------------------------------------------------------------
// Kernel 1 (fused): blocks 0..1023 = projections + exp(2x) [R3 version];
// blocks 1024..1279 = values fp32 [k][v] -> bf16 V^T [v][k] (64x64 LDS tiles).
__global__ __launch_bounds__(256) void proj_cvt_kernel(
    const float* __restrict__ queries, const float* __restrict__ keys,
    const float* __restrict__ W_q, const float* __restrict__ b_q,
    const float* __restrict__ W_k, const float* __restrict__ b_k,
    const float* __restrict__ values,
    float* __restrict__ eq, float* __restrict__ ek,
    unsigned short* __restrict__ vt)
{
    __shared__ float tile[64][65];

    if (blockIdx.x < 1024) {
        // ---- projection path (R3 proj, unchanged math)
        const int tid     = blockIdx.x * 256 + threadIdx.x;
        const int row     = tid >> 5;            // 0..8191
        const int sub     = tid & 31;
        const int h4      = (sub & 7) * 4;
        const int quarter = sub >> 3;            // 0..3 -> dims quarter*64..+63

        const float* src; const float* W; const float* bias; float* dst; int r;
        if (row < NB * NQ) { r = row;           src = queries + (size_t)r * DQK; W = W_q; bias = b_q; dst = eq; }
        else               { r = row - NB * NQ; src = keys    + (size_t)r * DQK; W = W_k; bias = b_k; dst = ek; }

        float a0 = 0.f, a1 = 0.f, a2 = 0.f, a3 = 0.f;
        if (quarter == 0) {
            float4 bv4 = *(const float4*)(bias + h4);
            a0 = bv4.x; a1 = bv4.y; a2 = bv4.z; a3 = bv4.w;
        }
        const int d0 = quarter * 64;
        #pragma unroll 4
        for (int i = d0; i < d0 + 64; i += 4) {
            float4 s  = *(const float4*)(src + i);
            float4 w0 = *(const float4*)(W + (size_t)(i + 0) * NH + h4);
            float4 w1 = *(const float4*)(W + (size_t)(i + 1) * NH + h4);
            float4 w2 = *(const float4*)(W + (size_t)(i + 2) * NH + h4);
            float4 w3 = *(const float4*)(W + (size_t)(i + 3) * NH + h4);
            a0 = fmaf(s.x, w0.x, a0); a1 = fmaf(s.x, w0.y, a1); a2 = fmaf(s.x, w0.z, a2); a3 = fmaf(s.x, w0.w, a3);
            a0 = fmaf(s.y, w1.x, a0); a1 = fmaf(s.y, w1.y, a1); a2 = fmaf(s.y, w1.z, a2); a3 = fmaf(s.y, w1.w, a3);
            a0 = fmaf(s.z, w2.x, a0); a1 = fmaf(s.z, w2.y, a1); a2 = fmaf(s.z, w2.z, a2); a3 = fmaf(s.z, w2.w, a3);
            a0 = fmaf(s.w, w3.x, a0); a1 = fmaf(s.w, w3.y, a1); a2 = fmaf(s.w, w3.z, a2); a3 = fmaf(s.w, w3.w, a3);
        }
        a0 += __shfl_xor(a0, 8, 64);  a1 += __shfl_xor(a1, 8, 64);
        a2 += __shfl_xor(a2, 8, 64);  a3 += __shfl_xor(a3, 8, 64);
        a0 += __shfl_xor(a0, 16, 64); a1 += __shfl_xor(a1, 16, 64);
        a2 += __shfl_xor(a2, 16, 64); a3 += __shfl_xor(a3, 16, 64);
        if (quarter == 0) {
            float4 o;
            o.x = __expf(2.f * a0); o.y = __expf(2.f * a1);
            o.z = __expf(2.f * a2); o.w = __expf(2.f * a3);
            *(float4*)(dst + (size_t)r * NH + h4) = o;
        }
    } else {
        // ---- values transpose path: 64k x 64v tile -> VT[b][v][k] bf16
        const int bx = blockIdx.x - 1024;        // 0..255
        const int b  = bx >> 6;
        const int rr = bx & 63;
        const int kt = rr & 15;                  // k-tile 0..15
        const int vtile = rr >> 4;               // v-tile 0..3
        const int t  = threadIdx.x;

        const float* src = values + ((size_t)b * NK + kt * 64) * NV + vtile * 64;
        const int kl = t >> 2;                   // 0..63
        const int vc = (t & 3) * 16;
        float4 x0 = *(const float4*)(src + (size_t)kl * NV + vc);
        float4 x1 = *(const float4*)(src + (size_t)kl * NV + vc + 4);
        float4 x2 = *(const float4*)(src + (size_t)kl * NV + vc + 8);
        float4 x3 = *(const float4*)(src + (size_t)kl * NV + vc + 12);
        *(float4*)&tile[kl][vc]      = x0;
        *(float4*)&tile[kl][vc + 4]  = x1;
        *(float4*)&tile[kl][vc + 8]  = x2;
        *(float4*)&tile[kl][vc + 12] = x3;
        __syncthreads();

        const int vl = t >> 2;                   // 0..63
        const int kc = (t & 3) * 16;
        union { unsigned short u[16]; uint4 q[2]; } o;
        #pragma unroll
        for (int j = 0; j < 16; j++)
            o.u[j] = (unsigned short)f32_to_bf16_rne(tile[kc + j][vl]);
        unsigned short* dst = vt + ((size_t)(b * NV + vtile * 64 + vl)) * NK + kt * 64 + kc;
        *(uint4*)dst       = o.q[0];
        *(uint4*)(dst + 8) = o.q[1];
    }
}

// ---------------------------------------------------------------------------
// Kernel 2: fused scores + softmax + MFMA weighted sum.
// Block = 512 (8 waves), handles (b, TQ=8 q-rows). grid = 4*128 = 512.
// Score: wave w covers contiguous k-chunk; lane = (qi=lane&7, kp=lane>>3)
//   computes k-pairs, packs 2 bf16 weights per b32 LDS write to s_w16[q][k].
// BMM: wave w owns v-cols [w*32, w*32+32) over ALL k; per 32-k step:
//   A-frag = ds_read_b128 from s_w16 (rows 8..15 zero), 2 B-frags from VT,
//   2 MFMA. C/D: col=lane&15 (v), row=(lane>>4)*4+reg (q; rows>=8 discarded).
__global__ __launch_bounds__(BLK, 4) void attn_kernel(
    const float* __restrict__ eq, const float* __restrict__ ek,
    const unsigned short* __restrict__ vt, const int* __restrict__ valid_lens,
    const float* __restrict__ w_v, float* __restrict__ out)
{
    __shared__ unsigned short s_w16[TQ][KSTR];  // 16.1 KB bf16 weights [q][k]
    __shared__ float s_part[8][TQ];             // per-wave softmax denom partials

    const int t      = threadIdx.x;
    const int b      = blockIdx.x >> 7;
    const int q0     = (blockIdx.x & 127) * TQ;
    const int nvalid = valid_lens[b];            // [1, 1024]
    const int kmax   = (nvalid + 31) & ~31;      // BMM k-extent (zero-padded)
    const int wave   = t >> 6;
    const int lane   = t & 63;
    const int qi     = lane & 7;
    const int kp     = lane >> 3;                // 0..7 -> k-pair within 16-chunk

    // score-phase k-chunk for this wave (multiple of 16)
    const int cw   = ((kmax >> 3) + 15) & ~15;
    const int kbeg = wave * cw;
    const int kend = min(kmax, kbeg + cw);

    float wv[NH];
    #pragma unroll
    for (int h = 0; h < NH; h += 4) {
        float4 w4 = *(const float4*)(w_v + h);
        wv[h] = w4.x; wv[h+1] = w4.y; wv[h+2] = w4.z; wv[h+3] = w4.w;
    }
    float eqr[NH];
    const float* eqp = eq + (size_t)(b * NQ + q0 + qi) * NH;
    #pragma unroll
    for (int h = 0; h < NH; h += 4) {
        float4 e4 = *(const float4*)(eqp + h);
        eqr[h] = e4.x; eqr[h+1] = e4.y; eqr[h+2] = e4.z; eqr[h+3] = e4.w;
    }

    // ---- scores + exp -> packed bf16 weight pairs into s_w16[qi][k]
    const float* ekbase = ek + (size_t)b * NK * NH;
    float ssum = 0.f;
    for (int k0 = kbeg; k0 < kend; k0 += 16) {
        const int k = k0 + 2 * kp;
        float e0 = 0.f, e1 = 0.f;
        #pragma unroll 2
        for (int s = 0; s < 2; s++) {
            if (k + s < nvalid) {
                const float* ekp = ekbase + (size_t)(k + s) * NH;
                float acc = 0.f;
                #pragma unroll
                for (int h = 0; h < NH; h += 4) {
                    float4 e4 = *(const float4*)(ekp + h);
                    float u0 = fmaf(eqr[h+0], e4.x, 1.f);
                    float u1 = fmaf(eqr[h+1], e4.y, 1.f);
                    float u2 = fmaf(eqr[h+2], e4.z, 1.f);
                    float u3 = fmaf(eqr[h+3], e4.w, 1.f);
                    float d01 = u0 * u1, d23 = u2 * u3;
                    float n01 = fmaf(wv[h+0], u1, wv[h+1] * u0);
                    float n23 = fmaf(wv[h+2], u3, wv[h+3] * u2);
                    float d   = fminf(d01 * d23, 1e38f);   // inf guard
                    float n   = fmaf(n01, d23, n23 * d01);
                    acc = fmaf(n, fast_rcp(d), acc);
                }
                float e = __expf(-2.f * acc);
                if (s == 0) e0 = e; else e1 = e;
            }
        }
        unsigned int pk = f32_to_bf16_rne(e0) | (f32_to_bf16_rne(e1) << 16);
        *(unsigned int*)&s_w16[qi][k] = pk;      // k even -> 4B aligned
        ssum += e0 + e1;
    }

    // per-wave softmax denominator partial (reduce over kp = lane bits 3..5)
    ssum += __shfl_xor(ssum, 8, 64);
    ssum += __shfl_xor(ssum, 16, 64);
    ssum += __shfl_xor(ssum, 32, 64);
    if (lane < TQ) s_part[wave][lane] = ssum;

    __syncthreads();   // all weights + denom partials visible

    // ---- MFMA bmm: this wave's 2 v-tiles (v0 = wave*32, +16) over k=[0,kmax)
    const int n    = lane & 15;
    const int quad = lane >> 4;
    f32x4 c0 = {0.f, 0.f, 0.f, 0.f};
    f32x4 c1 = {0.f, 0.f, 0.f, 0.f};
    const unsigned short* vt0 = vt + ((size_t)(b * NV + wave * 32 + n)) * NK + quad * 8;
    const unsigned short* vt1 = vt0 + (size_t)16 * NK;
    const unsigned short* arow = &s_w16[n & 7][quad * 8];   // valid row for n<8

    for (int k0 = 0; k0 < kmax; k0 += 32) {
        bf16x8 a = {0,0,0,0,0,0,0,0};
        if (n < 8) a = *(const bf16x8*)(arow + k0);
        bf16x8 b0 = *(const bf16x8*)(vt0 + k0);
        bf16x8 b1 = *(const bf16x8*)(vt1 + k0);
        c0 = __builtin_amdgcn_mfma_f32_16x16x32_bf16(a, b0, c0, 0, 0, 0);
        c1 = __builtin_amdgcn_mfma_f32_16x16x32_bf16(a, b1, c1, 0, 0, 0);
    }

    // ---- epilogue: rows 0..7 valid (quad 0,1); normalize and store
    if (quad < 2) {
        #pragma unroll
        for (int r = 0; r < 4; r++) {
            const int q = quad * 4 + r;
            float den = s_part[0][q] + s_part[1][q] + s_part[2][q] + s_part[3][q]
                      + s_part[4][q] + s_part[5][q] + s_part[6][q] + s_part[7][q];
            float rs = fast_rcp(den);
            float* ob = out + (size_t)(b * NQ + q0 + q) * NV + wave * 32 + n;
            ob[0]  = c0[r] * rs;
            ob[16] = c1[r] * rs;
        }
    }
}

// ---------------------------------------------------------------------------
extern "C" void kernel_launch(void* const* d_in, const int* in_sizes, int n_in,
                              void* d_out, int out_size, void* d_ws, size_t ws_size,
                              hipStream_t stream) {
    (void)in_sizes; (void)n_in; (void)out_size; (void)ws_size;
    const float* keys       = (const float*)d_in[0];
    const float* queries    = (const float*)d_in[1];
    const float* values     = (const float*)d_in[2];
    const int*   valid_lens = (const int*)d_in[3];
    const float* W_q        = (const float*)d_in[4];
    const float* b_q        = (const float*)d_in[5];
    const float* W_k        = (const float*)d_in[6];
    const float* b_k        = (const float*)d_in[7];
    const float* w_v        = (const float*)d_in[8];
    // d_in[9] = b_v: cancels in softmax.
    float* out = (float*)d_out;

    float* eq = (float*)d_ws;                                 // 512 KB
    float* ek = eq + (size_t)NB * NQ * NH;                    // 512 KB
    unsigned short* vt = (unsigned short*)(ek + (size_t)NB * NK * NH);  // V^T bf16, 2 MB

    proj_cvt_kernel<<<dim3(1280), dim3(256), 0, stream>>>(
        queries, keys, W_q, b_q, W_k, b_k, values, eq, ek, vt);
    attn_kernel<<<dim3(NB * (NQ / TQ)), dim3(BLK), 0, stream>>>(
        eq, ek, vt, valid_lens, w_v, out);
}